// Round 2
// baseline (364.256 us; speedup 1.0000x reference)
//
#include <hip/hip_runtime.h>

typedef _Float16 half_t;
typedef __attribute__((ext_vector_type(8))) _Float16 half8;
typedef __attribute__((ext_vector_type(4))) _Float16 half4;
typedef __attribute__((ext_vector_type(4))) float float4_t;

#define BN_EPS 1e-5f

constexpr int Nn = 64, Cc = 64, Tt = 300, Vv = 25, Ss = 3;
constexpr int TB   = 4;              // timesteps per tile (stage-2 N = 100)
constexpr int TPB  = 5;              // tiles per block -> 20 timesteps per block
constexpr int TWN  = TB * Vv;        // 100 = stage-2 N dimension
constexpr int NT   = 7;              // 7 n-tiles of 16 cover 112 >= 100
constexpr int XL_T = 32;             // v-stride (padded 25->32, pads are ZERO = free K-pad)
constexpr int XL_C = TB * XL_T + 8;  // 136 halfs per c row
constexpr int XA_S = 72;             // c-stride of xa rows (144 B, 16B-aligned)
constexpr int XA_R = NT * 16;        // 112 rows
constexpr int AE_S = 40;             // v-stride of transient AeT rows
constexpr int NPF  = 7;              // ceil(1600 float4 / 256 threads)

__global__ __launch_bounds__(256, 4)
void gcn_fused(const float* __restrict__ x,   const float* __restrict__ A,
               const float* __restrict__ PA1, const float* __restrict__ PA2,
               const float* __restrict__ Wc,  const float* __restrict__ bc,
               const float* __restrict__ gamma, const float* __restrict__ beta,
               const float* __restrict__ rmean, const float* __restrict__ rvar,
               float* __restrict__ out)
{
    __shared__ __align__(16) half_t Xl[Cc * XL_C];       // 17408 B
    __shared__ __align__(16) half_t xaL[XA_R * XA_S];    // 16128 B
    __shared__ float bnsc[Cc], bnsh[Cc];                 // 512 B  (~34 KB -> 4 blocks/CU)

    // AeT staged TRANSIENTLY into xaL region (3*32*40 = 3840 halfs), consumed into
    // registers before stage-1 ever writes xaL.
    half_t* AeU = xaL;

    const int tid  = threadIdx.x;
    const int lane = tid & 63;
    const int wave = tid >> 6;      // 0..3
    const int col  = lane & 15;     // MFMA n/m lane index
    const int quad = lane >> 4;     // 0..3

    const int g = blockIdx.x;       // 0..14  (t-group)
    const int n = blockIdx.y;       // 0..63
    const int tbase = g * (TB * TPB);   // 20-timestep chunk, exact (300 = 15*20)

    // ---- BN scale/shift with Sum_s bc[s] folded in ----
    if (tid < Cc) {
        float sc   = gamma[tid] * rsqrtf(rvar[tid] + BN_EPS);
        float bsum = bc[tid] + bc[Cc + tid] + bc[2 * Cc + tid];
        bnsc[tid] = sc;
        bnsh[tid] = beta[tid] - rmean[tid] * sc + bsum * sc;
    }

    // ---- adaptive adjacency, transposed, into the transient AeU region ----
    for (int e = tid; e < Ss * 32 * 32; e += 256) {
        int s = e >> 10, r = e & 1023, w = r >> 5, v = r & 31;
        float val = 0.f;
        if (v < Vv && w < Vv) {
            int ai = (s * Vv + v) * Vv + w;
            val = A[ai] * PA1[ai] + PA2[ai];
        }
        AeU[(s * 32 + w) * AE_S + v] = (half_t)val;
    }

    // ---- zero the xa tail rows 100..111 (halfs 7200.. : disjoint from AeU's 0..3839) ----
    for (int e = tid; e < (XA_R - TWN) * XA_S; e += 256)
        xaL[TWN * XA_S + e] = (half_t)0.f;

    // ---- zero the Xl v-pads (v = 25..31 for each (c,t)); never overwritten later ----
    for (int e = tid; e < Cc * TB * 7; e += 256) {
        int c = e / 28, r = e % 28, t = r / 7, v = 25 + r % 7;
        Xl[c * XL_C + t * XL_T + v] = (half_t)0.f;
    }

    // ---- Wc A-fragments (this wave's o-tile), float4 loads, fp32 -> fp16, in registers ----
    half8 wf[Ss][2];
    {
        int o = wave * 16 + col;                 // A-frag: m = lane&15
        #pragma unroll
        for (int s = 0; s < Ss; ++s)
            #pragma unroll
            for (int ks = 0; ks < 2; ++ks) {
                const float* p = Wc + (s * Cc + o) * Cc + ks * 32 + quad * 8; // k = quad*8+j
                float4_t a = *(const float4_t*)p;
                float4_t b = *(const float4_t*)(p + 4);
                half8 h;
                #pragma unroll
                for (int j = 0; j < 4; ++j) { h[j] = (half_t)a[j]; h[4 + j] = (half_t)b[j]; }
                wf[s][ks] = h;
            }
    }

    // ---- issue tile-0 x prefetch into registers (consumed at first Xl write) ----
    const float* xb = x + (size_t)n * Cc * Tt * Vv + tbase * Vv;
    float4_t pf[NPF];
    #pragma unroll
    for (int k = 0; k < NPF; ++k) {
        int i = tid + k * 256;
        if (i < Cc * (TWN / 4)) {
            int c = i / 25, kk = i - c * 25;
            pf[k] = *(const float4_t*)(xb + c * (Tt * Vv) + kk * 4);   // 16B-aligned
        }
    }
    __syncthreads();

    // ---- Ae B-frags for ALL s into registers, then the AeU region is dead ----
    half8 ab[Ss][2];
    #pragma unroll
    for (int s = 0; s < Ss; ++s)
        #pragma unroll
        for (int wt = 0; wt < 2; ++wt)
            ab[s][wt] = *(const half8*)&AeU[(s * 32 + wt * 16 + col) * AE_S + quad * 8];
    __syncthreads();   // all waves done reading AeU before stage-1 writes xaL

    const float4_t zero4 = {0.f, 0.f, 0.f, 0.f};
    const int t = wave;   // each wave owns one timestep of the 4

    for (int tile = 0; tile < TPB; ++tile) {
        // ---- write Xl from prefetch regs (vmcnt wait lands here), de-interleaved ----
        #pragma unroll
        for (int k = 0; k < NPF; ++k) {
            int i = tid + k * 256;
            if (i < Cc * (TWN / 4)) {
                int c = i / 25, kk = i - c * 25;
                int p = kk * 4;
                #pragma unroll
                for (int j = 0; j < 4; ++j) {
                    int gg = p + j;
                    int tt = gg / 25, v = gg - tt * 25;
                    Xl[c * XL_C + tt * XL_T + v] = (half_t)pf[k][j];
                }
            }
        }
        __syncthreads();

        // ---- issue next tile's x loads; they complete during the s-loop below ----
        if (tile + 1 < TPB) {
            const float* xn = xb + (tile + 1) * TWN;
            #pragma unroll
            for (int k = 0; k < NPF; ++k) {
                int i = tid + k * 256;
                if (i < Cc * (TWN / 4)) {
                    int c = i / 25, kk = i - c * 25;
                    pf[k] = *(const float4_t*)(xn + c * (Tt * Vv) + kk * 4);
                }
            }
        }

        float4_t yacc[NT];
        #pragma unroll
        for (int i = 0; i < NT; ++i) yacc[i] = zero4;

        #pragma unroll
        for (int s = 0; s < Ss; ++s) {
            // ---- stage 1: xa[c][(t,w)] = X · Ae[s], K=32 covers v=25 (zero-padded) ----
            #pragma unroll
            for (int ct = 0; ct < 4; ++ct) {
                // A-frag: m = c = ct*16+col, k = v = quad*8+j
                half8 af = *(const half8*)&Xl[(ct * 16 + col) * XL_C + t * XL_T + quad * 8];
                #pragma unroll
                for (int wt = 0; wt < 2; ++wt) {
                    float4_t r = __builtin_amdgcn_mfma_f32_16x16x32_f16(af, ab[s][wt], zero4, 0, 0, 0);
                    int w = wt * 16 + col;           // C/D: col = lane&15
                    if (w < Vv) {
                        half4 h;
                        #pragma unroll
                        for (int i2 = 0; i2 < 4; ++i2) h[i2] = (half_t)r[i2]; // rows = quad*4+i = consecutive c
                        *(half4*)&xaL[(t * Vv + w) * XA_S + ct * 16 + quad * 4] = h;
                    }
                }
            }
            __syncthreads();

            // ---- stage 2: y[o][(t,w)] += Wc[s] · xa  (M=64 over waves, N=112, K=64) ----
            #pragma unroll
            for (int nt = 0; nt < NT; ++nt) {
                int tw = nt * 16 + col;              // B-frag: n = tw
                #pragma unroll
                for (int ks = 0; ks < 2; ++ks) {
                    half8 bf = *(const half8*)&xaL[tw * XA_S + ks * 32 + quad * 8]; // k = c
                    yacc[nt] = __builtin_amdgcn_mfma_f32_16x16x32_f16(wf[s][ks], bf, yacc[nt], 0, 0, 0);
                }
            }
            if (s != Ss - 1) __syncthreads();        // xaL rewritten next s
        }

        // ---- epilogue: BN + residual (from Xl) + ReLU, coalesced stores ----
        float* ob = out + (size_t)n * Cc * Tt * Vv + (tbase + tile * TB) * Vv;
        #pragma unroll
        for (int nt = 0; nt < NT; ++nt) {
            int tw = nt * 16 + col;
            if (tw < TWN) {
                int tt = tw / 25;
                int w  = tw - tt * 25;
                #pragma unroll
                for (int i = 0; i < 4; ++i) {
                    int o = wave * 16 + quad * 4 + i;
                    float val = yacc[nt][i] * bnsc[o] + bnsh[o];
                    val += (float)Xl[o * XL_C + tt * XL_T + w];   // residual
                    ob[o * Tt * Vv + tw] = fmaxf(val, 0.f);       // contiguous in tw
                }
            }
        }

        // protect Xl (epilogue reads) and xaL (stage-2 reads) before next tile rewrites
        if (tile + 1 < TPB) __syncthreads();
    }
}

extern "C" void kernel_launch(void* const* d_in, const int* in_sizes, int n_in,
                              void* d_out, int out_size, void* d_ws, size_t ws_size,
                              hipStream_t stream) {
    const float* x     = (const float*)d_in[0];
    const float* A     = (const float*)d_in[1];
    const float* PA1   = (const float*)d_in[2];
    const float* PA2   = (const float*)d_in[3];
    const float* Wc    = (const float*)d_in[4];
    const float* bc    = (const float*)d_in[5];
    const float* gamma = (const float*)d_in[6];
    const float* beta  = (const float*)d_in[7];
    const float* rmean = (const float*)d_in[8];
    const float* rvar  = (const float*)d_in[9];
    float* out = (float*)d_out;

    dim3 grid(Tt / (TB * TPB), Nn);   // (15, 64) = 960 blocks, single co-resident round
    gcn_fused<<<grid, 256, 0, stream>>>(x, A, PA1, PA2, Wc, bc, gamma, beta, rmean, rvar, out);
}

// Round 3
// 319.412 us; speedup vs baseline: 1.1404x; 1.1404x over previous
//
#include <hip/hip_runtime.h>

typedef _Float16 half_t;
typedef __attribute__((ext_vector_type(8))) _Float16 half8;
typedef __attribute__((ext_vector_type(4))) _Float16 half4;
typedef __attribute__((ext_vector_type(4))) float float4_t;
typedef float f4u __attribute__((ext_vector_type(4), aligned(4)));  // 4B-aligned float4

#define BN_EPS 1e-5f

constexpr int Nn = 64, Cc = 64, Tt = 300, Vv = 25, Ss = 3;
constexpr int XA_S = 72;   // c-stride of wave-private xa rows (144 B: 16B-aligned, ~2-way banks)

// ---------------- precompute: fragment-major fp16 tables into workspace ----------------
// aeh[s][wt][lane][8] : Ae^T fragment  B[k=v][n=w], v=(lane>>4)*8+j, w=wt*16+(lane&15), zero-padded
// wch[s][ot][ks][lane][8] : Wc fragment A[m=o][k=c], o=ot*16+(lane&15), c=ks*32+(lane>>4)*8+j
// bnsc/bnsh[64] : BN scale/shift with sum_s bc folded in
__global__ __launch_bounds__(256, 1)
void gcn_pre(const float* __restrict__ A,   const float* __restrict__ PA1,
             const float* __restrict__ PA2, const float* __restrict__ Wc,
             const float* __restrict__ bc,  const float* __restrict__ gamma,
             const float* __restrict__ beta, const float* __restrict__ rmean,
             const float* __restrict__ rvar,
             half_t* __restrict__ aeh, half_t* __restrict__ wch,
             float* __restrict__ bnsc, float* __restrict__ bnsh)
{
    const int tid = threadIdx.x;
    if (tid < Cc) {
        float sc   = gamma[tid] * rsqrtf(rvar[tid] + BN_EPS);
        float bsum = bc[tid] + bc[Cc + tid] + bc[2 * Cc + tid];
        bnsc[tid] = sc;
        bnsh[tid] = beta[tid] - rmean[tid] * sc + bsum * sc;
    }
    for (int e = tid; e < Ss * 2 * 64; e += 256) {        // AeT fragments
        int s = e >> 7, wt = (e >> 6) & 1, lane = e & 63;
        int col = lane & 15, q = lane >> 4;
        int w = wt * 16 + col;
        #pragma unroll
        for (int j = 0; j < 8; ++j) {
            int v = q * 8 + j;
            float val = 0.f;
            if (v < Vv && w < Vv) {
                int ai = (s * Vv + v) * Vv + w;
                val = A[ai] * PA1[ai] + PA2[ai];
            }
            aeh[e * 8 + j] = (half_t)val;
        }
    }
    for (int e = tid; e < Ss * 4 * 2 * 64; e += 256) {    // Wc fragments
        int s = e >> 9, r = e & 511, ot = r >> 7, ks = (r >> 6) & 1, lane = r & 63;
        int col = lane & 15, q = lane >> 4;
        int o = ot * 16 + col;
        #pragma unroll
        for (int j = 0; j < 8; ++j) {
            int c = ks * 32 + q * 8 + j;
            wch[e * 8 + j] = (half_t)Wc[(s * Cc + o) * Cc + c];
        }
    }
}

// ---------------- main: barrier-free, wave-owns-timestep ----------------
__global__ __launch_bounds__(256, 4)
void gcn_main(const float* __restrict__ x, const half_t* __restrict__ aeh,
              const half_t* __restrict__ wch, const float* __restrict__ bnsc,
              const float* __restrict__ bnsh, float* __restrict__ out)
{
    // wave-private xa: [wave][s&1 dbuf][w 0..31][c 0..63 +pad]  = 36864 B total
    __shared__ __align__(16) half_t xaW[4][2][32][XA_S];

    const int tid  = threadIdx.x;
    const int lane = tid & 63;
    const int wave = tid >> 6;      // 0..3 -> owns timestep tg
    const int col  = lane & 15;
    const int quad = lane >> 4;

    const int n  = blockIdx.y;
    const int tg = blockIdx.x * 4 + wave;     // 0..299 exact

    // ---- Ae^T B-fragments, all s, from precomputed table (L3-hot) ----
    half8 ab[Ss][2];
    #pragma unroll
    for (int s = 0; s < Ss; ++s)
        #pragma unroll
        for (int wt = 0; wt < 2; ++wt)
            ab[s][wt] = *(const half8*)&aeh[((s * 2 + wt) * 64 + lane) * 8];

    // ---- x A-fragments direct from global: af[ct] = x[c=ct*16+col][tg][v=quad*8+j] ----
    half8 af[4];
    #pragma unroll
    for (int ct = 0; ct < 4; ++ct) {
        const float* p = x + ((size_t)(n * Cc + ct * 16 + col) * Tt + tg) * Vv;
        half8 h;
        if (quad < 3) {
            f4u a0 = *(const f4u*)(p + quad * 8);      // rows are 100B-strided: 4B-aligned
            f4u a1 = *(const f4u*)(p + quad * 8 + 4);
            #pragma unroll
            for (int j = 0; j < 4; ++j) { h[j] = (half_t)a0[j]; h[4 + j] = (half_t)a1[j]; }
        } else {
            h[0] = (half_t)p[24];                      // v=24; v=25..31 are K-pad zeros
            #pragma unroll
            for (int j = 1; j < 8; ++j) h[j] = (half_t)0.f;
        }
        af[ct] = h;
    }

    const float4_t zero4 = {0.f, 0.f, 0.f, 0.f};
    float4_t yacc[4][2];
    #pragma unroll
    for (int ot = 0; ot < 4; ++ot)
        #pragma unroll
        for (int wt = 0; wt < 2; ++wt) yacc[ot][wt] = zero4;

    #pragma unroll
    for (int s = 0; s < Ss; ++s) {
        const int sb = s & 1;
        // ---- stage 1: xa[c][w] = x · Ae[s] for this wave's t (8 MFMA) ----
        // D[m=c=ct*16+quad*4+i][n=w=wt*16+col]; Ae cols w>=25 are zero -> rows 25..31 = 0
        #pragma unroll
        for (int ct = 0; ct < 4; ++ct)
            #pragma unroll
            for (int wt = 0; wt < 2; ++wt) {
                float4_t r = __builtin_amdgcn_mfma_f32_16x16x32_f16(af[ct], ab[s][wt], zero4, 0, 0, 0);
                half4 h;
                #pragma unroll
                for (int i = 0; i < 4; ++i) h[i] = (half_t)r[i];
                *(half4*)&xaW[wave][sb][wt * 16 + col][ct * 16 + quad * 4] = h;
            }
        // ---- same-wave transpose readback: B[k=c=ks*32+quad*8+j][n=w=wt*16+col] ----
        // (write->read same wave: lgkmcnt ordering, NO barrier)
        half8 bf[2][2];
        #pragma unroll
        for (int ks = 0; ks < 2; ++ks)
            #pragma unroll
            for (int wt = 0; wt < 2; ++wt)
                bf[ks][wt] = *(const half8*)&xaW[wave][sb][wt * 16 + col][ks * 32 + quad * 8];
        // ---- stage 2: y[o][w] += Wc[s] · xa  (16 MFMA), wf streamed from L2 table ----
        #pragma unroll
        for (int ot = 0; ot < 4; ++ot) {
            half8 w0 = *(const half8*)&wch[(((s * 4 + ot) * 2 + 0) * 64 + lane) * 8];
            half8 w1 = *(const half8*)&wch[(((s * 4 + ot) * 2 + 1) * 64 + lane) * 8];
            #pragma unroll
            for (int wt = 0; wt < 2; ++wt) {
                yacc[ot][wt] = __builtin_amdgcn_mfma_f32_16x16x32_f16(w0, bf[0][wt], yacc[ot][wt], 0, 0, 0);
                yacc[ot][wt] = __builtin_amdgcn_mfma_f32_16x16x32_f16(w1, bf[1][wt], yacc[ot][wt], 0, 0, 0);
            }
        }
    }

    // ---- epilogue: BN + residual (x re-read, L1/L2-hot) + ReLU ----
    const size_t base = (size_t)n * Cc * Tt * Vv + (size_t)tg * Vv;
    const float* xr   = x + base;
    float* outr       = out + base;
    #pragma unroll
    for (int ot = 0; ot < 4; ++ot) {
        float4_t sc = *(const float4_t*)&bnsc[ot * 16 + quad * 4];   // 16B-aligned, L3-hot
        float4_t sh = *(const float4_t*)&bnsh[ot * 16 + quad * 4];
        #pragma unroll
        for (int i = 0; i < 4; ++i) {
            const size_t ro = (size_t)(ot * 16 + quad * 4 + i) * (Tt * Vv);
            #pragma unroll
            for (int wt = 0; wt < 2; ++wt) {
                int w = wt * 16 + col;
                if (w < Vv) {
                    float val = yacc[ot][wt][i] * sc[i] + sh[i] + xr[ro + w];
                    outr[ro + w] = fmaxf(val, 0.f);
                }
            }
        }
    }
}

extern "C" void kernel_launch(void* const* d_in, const int* in_sizes, int n_in,
                              void* d_out, int out_size, void* d_ws, size_t ws_size,
                              hipStream_t stream) {
    const float* x     = (const float*)d_in[0];
    const float* A     = (const float*)d_in[1];
    const float* PA1   = (const float*)d_in[2];
    const float* PA2   = (const float*)d_in[3];
    const float* Wc    = (const float*)d_in[4];
    const float* bc    = (const float*)d_in[5];
    const float* gamma = (const float*)d_in[6];
    const float* beta  = (const float*)d_in[7];
    const float* rmean = (const float*)d_in[8];
    const float* rvar  = (const float*)d_in[9];
    float* out = (float*)d_out;

    // workspace layout (37,376 B): aeh | wch | bnsc | bnsh
    half_t* aeh = (half_t*)d_ws;                      // 3*2*64*8  = 3072 halfs
    half_t* wch = aeh + Ss * 2 * 64 * 8;              // 3*4*2*64*8 = 12288 halfs
    float* bnsc = (float*)(wch + Ss * 4 * 2 * 64 * 8);
    float* bnsh = bnsc + Cc;

    gcn_pre<<<dim3(1), 256, 0, stream>>>(A, PA1, PA2, Wc, bc, gamma, beta, rmean, rvar,
                                         aeh, wch, bnsc, bnsh);
    gcn_main<<<dim3(Tt / 4, Nn), 256, 0, stream>>>(x, aeh, wch, bnsc, bnsh, out);
}